// Round 8
// baseline (1793.016 us; speedup 1.0000x reference)
//
#include <hip/hip_runtime.h>

typedef short s16x8 __attribute__((ext_vector_type(8)));
typedef float f32x4 __attribute__((ext_vector_type(4)));

// device-global scratch (outside d_ws; fully rewritten every launch)
__device__ short g_wbuf[3145728];   // per-layer bf16 weights: inproj|outw|ffw1|ffw2
__device__ short g_srcb[1048576];   // src as bf16 (16384 x 64)
__device__ short g_inpwb[32768];    // inp_w as bf16 (512 x 64)
__device__ float g_pe[262144];      // positional encoding (512 x 512)
__device__ float g_hpart[256];      // head partials

__device__ inline float b2f(short s) {
  union { unsigned int u; float f; } v;
  v.u = ((unsigned int)(unsigned short)s) << 16;
  return v.f;
}
__device__ inline short f2b(float f) {
  union { float f; unsigned int u; } v; v.f = f;
  unsigned int r = (v.u + 0x7fffu + ((v.u >> 16) & 1u)) >> 16;
  return (short)r;
}
__device__ inline s16x8 pack8(float4 a, float4 b) {
  s16x8 r;
  r[0] = f2b(a.x); r[1] = f2b(a.y); r[2] = f2b(a.z); r[3] = f2b(a.w);
  r[4] = f2b(b.x); r[5] = f2b(b.y); r[6] = f2b(b.z); r[7] = f2b(b.w);
  return r;
}

__device__ inline f32x4 mfma16(s16x8 a, s16x8 b, f32x4 c) {
  return __builtin_amdgcn_mfma_f32_16x16x32_bf16(a, b, c, 0, 0, 0);
}

typedef const __attribute__((address_space(1))) void* as1cptr;
typedef __attribute__((address_space(3))) void* as3ptr;
__device__ inline void gl2lds16(const short* g, short* l) {
  __builtin_amdgcn_global_load_lds((as1cptr)g, (as3ptr)l, 16, 0, 0);
}

// ---------------- fp32 -> bf16 conversion kernels --------------------------
__global__ void __launch_bounds__(256)
cvt2_kernel(const float* __restrict__ i0, const float* __restrict__ i1) {
  const int b = blockIdx.x;
  const float* src; short* dst; int base;
  if (b < 512) { src = i0; dst = g_srcb; base = b; }
  else         { src = i1; dst = g_inpwb; base = b - 512; }
  const int idx = (base * 256 + threadIdx.x) * 8;
  float4 a = *(const float4*)(src + idx);
  float4 c = *(const float4*)(src + idx + 4);
  *(s16x8*)(dst + idx) = pack8(a, c);
}

__global__ void __launch_bounds__(256)
cvt4_kernel(const float* __restrict__ i0, const float* __restrict__ i1,
            const float* __restrict__ i2, const float* __restrict__ i3) {
  const int b = blockIdx.x;
  const float* src; short* dst; int base;
  if (b < 384)       { src = i0; dst = g_wbuf;           base = b; }
  else if (b < 512)  { src = i1; dst = g_wbuf +  786432; base = b - 384; }
  else if (b < 1024) { src = i2; dst = g_wbuf + 1048576; base = b - 512; }
  else               { src = i3; dst = g_wbuf + 2097152; base = b - 1024; }
  const int idx = (base * 256 + threadIdx.x) * 8;
  float4 a = *(const float4*)(src + idx);
  float4 c = *(const float4*)(src + idx + 4);
  *(s16x8*)(dst + idx) = pack8(a, c);
}

// ---------------- PE table: g_pe[s][n] ------------------------------------
__global__ void __launch_bounds__(256)
pe_kernel() {
  const int s = blockIdx.x;
  const int n0 = threadIdx.x * 2;
  const float ang = (float)s * expf((float)n0 * -0.0179889460390160f);
  g_pe[s * 512 + n0]     = sinf(ang);
  g_pe[s * 512 + n0 + 1] = cosf(ang);
}

// ---------------- GEMM: C[M,N] = A[M,K] @ W[N,K]^T + epilogue -------------
// BK=64, XOR-swizzled gl2lds staging. 1D grid, bn-major decode
// (bm = id&127, bn = id>>7): same-XCD blocks (stride 8) share one W-tile
// chunk -> per-XCD L2 W traffic /16; A-tiles get XCD affinity (bm%8 fixed).
// EPI: 0 = +bias; 1 = relu(+bias); 2 = embed ((acc+bias)*sqrt512 + PE)
template <int EPI>
__global__ void __launch_bounds__(256, 3)
gemm_bt(const short* __restrict__ Ain, int woff, const float* __restrict__ bias,
        short* __restrict__ C, int M, int N, int K) {
  __shared__ short As[128 * 64];   // 16 KB
  __shared__ short Bs[128 * 64];   // 16 KB
  const int tid  = threadIdx.x;
  const int lane = tid & 63;
  const int wave = tid >> 6;
  const int wr = (wave >> 1) << 6;
  const int wc = (wave & 1) << 6;
  const int ml = lane & 15;
  const int quad = lane >> 4;
  const int bm = blockIdx.x & 127;
  const int bn = blockIdx.x >> 7;

  const short* A = (EPI == 2) ? (const short*)g_srcb : Ain;
  const short* W = (EPI == 2) ? (const short*)g_inpwb : (const short*)(g_wbuf + woff);

  int srow[4], soff[4];
#pragma unroll
  for (int i = 0; i < 4; ++i) {
    const int u = i * 256 + tid;
    srow[i] = u >> 3;
    soff[i] = ((u & 7) ^ ((u >> 3) & 7)) << 3;
  }
  const int rsw = (ml & 7);
  f32x4 acc[4][4] = {};

  for (int k0 = 0; k0 < K; k0 += 64) {
#pragma unroll
    for (int i = 0; i < 4; ++i) {
      gl2lds16(A + (size_t)(bm * 128 + srow[i]) * K + k0 + soff[i],
               As + (i * 256 + tid) * 8);
      gl2lds16(W + (size_t)(bn * 128 + srow[i]) * K + k0 + soff[i],
               Bs + (i * 256 + tid) * 8);
    }
    __syncthreads();
#pragma unroll
    for (int kk = 0; kk < 2; ++kk) {
      const int rchunk = ((kk * 4 + quad) ^ rsw) * 8;
      s16x8 af[4], bfr[4];
#pragma unroll
      for (int i = 0; i < 4; ++i)
        af[i] = *(const s16x8*)(As + (wr + i * 16 + ml) * 64 + rchunk);
#pragma unroll
      for (int j = 0; j < 4; ++j)
        bfr[j] = *(const s16x8*)(Bs + (wc + j * 16 + ml) * 64 + rchunk);
#pragma unroll
      for (int i = 0; i < 4; ++i)
#pragma unroll
        for (int j = 0; j < 4; ++j)
          acc[i][j] = mfma16(af[i], bfr[j], acc[i][j]);
    }
    __syncthreads();
  }

#pragma unroll
  for (int j = 0; j < 4; ++j) {
    const int col = bn * 128 + wc + j * 16 + ml;
    const float bv = bias[col];
#pragma unroll
    for (int i = 0; i < 4; ++i) {
      const int row0 = bm * 128 + wr + i * 16 + quad * 4;
#pragma unroll
      for (int r = 0; r < 4; ++r) {
        float v = acc[i][j][r] + bv;
        if (EPI == 1) v = fmaxf(v, 0.0f);
        if (EPI == 2) {
          const int s = (row0 + r) & 511;
          v = (acc[i][j][r] + bv) * 22.62741699796952f + g_pe[s * 512 + col];
        }
        C[(size_t)(row0 + r) * N + col] = f2b(v);
      }
    }
  }
}

// ---------------- fused attention, single pass, 64-key rounds -------------
// LDS shrunk to ~23.3 KB (KT 9K + VT 9K + Pt 4.6K) -> 5+ blocks/CU resident
// (was 44 KB -> 3). 8 rounds of 64 keys; scores in regs sc[8][2].
__global__ void __launch_bounds__(256, 5)
attn_kernel(const short* __restrict__ qkv, short* __restrict__ ctx) {
  __shared__ short KT[64 * 72];      // 9216 B  [key][d]
  __shared__ short VT[64 * 72];      // 9216 B  [d][key]
  __shared__ short Pt[32 * 72];      // 4608 B  [qrow][key]
  __shared__ float rcomb[2][2][16];  // [nh][mt][row16]: max, then sums
  const int tid = threadIdx.x;
  const int lane = tid & 63, wave = tid >> 6;
  const int ml = lane & 15, quad = lane >> 4;
  const int mt = wave & 1, nh = wave >> 1;
  const int bx = blockIdx.x;
  const int qt = bx >> 8;
  const int bh = bx & 255;
  const int b = bh >> 3, h = bh & 7;
  const size_t basebs = (size_t)b * 512 * 1536;
  const int hoff = h * 64;

  s16x8 qf0, qf1;
  {
    const int qrow = qt * 32 + mt * 16 + ml;
    const short* qp = qkv + basebs + (size_t)qrow * 1536 + hoff;
    qf0 = *(const s16x8*)(qp + quad * 8);
    qf1 = *(const s16x8*)(qp + 32 + quad * 8);
  }

  // ---- phase 1: all scores into registers (8 rounds x 64 keys) ----
  f32x4 sc[8][2];
#pragma unroll
  for (int rr = 0; rr < 8; ++rr) {
#pragma unroll
    for (int i = 0; i < 2; ++i) {          // stage 64 keys x 64 d
      int u = i * 256 + tid;
      int key = u >> 3;
      int d8 = (u & 7) << 3;
      const short* kp = qkv + basebs + (size_t)(rr * 64 + key) * 1536 + 512 + hoff + d8;
      *(s16x8*)(KT + key * 72 + d8) = *(const s16x8*)kp;
    }
    __syncthreads();
#pragma unroll
    for (int nt = 0; nt < 2; ++nt) {
      const int nrow = nh * 32 + nt * 16 + ml;
      f32x4 sacc = {};
      s16x8 kf0 = *(const s16x8*)(KT + nrow * 72 + quad * 8);
      s16x8 kf1 = *(const s16x8*)(KT + nrow * 72 + 32 + quad * 8);
      sacc = mfma16(qf0, kf0, sacc);
      sacc = mfma16(qf1, kf1, sacc);
      sc[rr][nt] = sacc;
    }
    __syncthreads();
  }

  // ---- exact row max ----
  f32x4 rmx = sc[0][0];
#pragma unroll
  for (int rr = 0; rr < 8; ++rr)
#pragma unroll
    for (int nt = 0; nt < 2; ++nt)
#pragma unroll
      for (int r = 0; r < 4; ++r)
        rmx[r] = fmaxf(rmx[r], sc[rr][nt][r]);
#pragma unroll
  for (int off = 1; off <= 8; off <<= 1)
#pragma unroll
    for (int r = 0; r < 4; ++r)
      rmx[r] = fmaxf(rmx[r], __shfl_xor(rmx[r], off));
  if (ml == 0) {
#pragma unroll
    for (int r = 0; r < 4; ++r)
      rcomb[nh][mt][quad * 4 + r] = rmx[r];
  }
  __syncthreads();
  float rm[4];
#pragma unroll
  for (int r = 0; r < 4; ++r)
    rm[r] = 0.125f * fmaxf(rcomb[0][mt][quad * 4 + r], rcomb[1][mt][quad * 4 + r]);

  // ---- phase 2: exp -> Pt, V^T stage, PV MFMA (8 rounds) ----
  f32x4 oacc[2] = {};
  float psum[4] = {0.f, 0.f, 0.f, 0.f};
#pragma unroll
  for (int rr = 0; rr < 8; ++rr) {
#pragma unroll
    for (int nt = 0; nt < 2; ++nt) {
#pragma unroll
      for (int r = 0; r < 4; ++r) {
        float p = __expf(sc[rr][nt][r] * 0.125f - rm[r]);   // arg <= 0 exactly
        short pb = f2b(p);
        psum[r] += b2f(pb);
        Pt[(mt * 16 + quad * 4 + r) * 72 + nh * 32 + nt * 16 + ml] = pb;
      }
    }
#pragma unroll
    for (int i = 0; i < 4; ++i) {          // stage V^T tile [d][key]
      int u = i * 256 + tid;
      int kp = u >> 5;   // key pair 0..31
      int dp = u & 31;   // d pair 0..31
      const short* vp = qkv + basebs + (size_t)(rr * 64 + kp * 2) * 1536 + 1024 + hoff + dp * 2;
      unsigned int u0 = *(const unsigned int*)vp;
      unsigned int u1 = *(const unsigned int*)(vp + 1536);
      unsigned int w0 = (u0 & 0xffffu) | (u1 << 16);
      unsigned int w1 = (u0 >> 16) | (u1 & 0xffff0000u);
      *(unsigned int*)(VT + (dp * 2) * 72 + kp * 2) = w0;
      *(unsigned int*)(VT + (dp * 2 + 1) * 72 + kp * 2) = w1;
    }
    __syncthreads();   // Pt + VT visible
#pragma unroll
    for (int ks = 0; ks < 2; ++ks) {
      s16x8 pf = *(const s16x8*)(Pt + (mt * 16 + ml) * 72 + ks * 32 + quad * 8);
#pragma unroll
      for (int n2 = 0; n2 < 2; ++n2) {
        const int nd = (nh * 2 + n2) * 16 + ml;
        s16x8 vf = *(const s16x8*)(VT + nd * 72 + ks * 32 + quad * 8);
        oacc[n2] = mfma16(pf, vf, oacc[n2]);
      }
    }
    __syncthreads();   // PV reads done before next-round Pt/VT rewrite
  }

  // ---- row sums ----
#pragma unroll
  for (int off = 1; off <= 8; off <<= 1)
#pragma unroll
    for (int r = 0; r < 4; ++r)
      psum[r] += __shfl_xor(psum[r], off);
  if (ml == 0) {
#pragma unroll
    for (int r = 0; r < 4; ++r)
      rcomb[nh][mt][quad * 4 + r] = psum[r];
  }
  __syncthreads();

#pragma unroll
  for (int r = 0; r < 4; ++r) {
    const int srow = mt * 16 + quad * 4 + r;
    const float l = rcomb[0][mt][quad * 4 + r] + rcomb[1][mt][quad * 4 + r];
    const float rl = 1.0f / l;
    const int grow = qt * 32 + srow;
#pragma unroll
    for (int n2 = 0; n2 < 2; ++n2) {
      const int d = (nh * 2 + n2) * 16 + ml;
      ctx[((size_t)b * 512 + grow) * 512 + hoff + d] = f2b(oacc[n2][r] * rl);
    }
  }
}

// ---------------- residual + layernorm (in-place on x, fp32 params) -------
__global__ void __launch_bounds__(256)
ln_kernel(short* __restrict__ x, const short* __restrict__ o,
          const float* __restrict__ g, const float* __restrict__ bta) {
  const int row = blockIdx.x * 4 + (threadIdx.x >> 6);
  const int lane = threadIdx.x & 63;
  short* xp = x + (size_t)row * 512 + lane * 8;
  const short* op = o + (size_t)row * 512 + lane * 8;
  s16x8 xv = *(const s16x8*)xp;
  s16x8 ov = *(const s16x8*)op;
  float v[8]; float s = 0.f, s2 = 0.f;
#pragma unroll
  for (int e = 0; e < 8; ++e) {
    float f = b2f(xv[e]) + b2f(ov[e]);
    v[e] = f; s += f; s2 += f * f;
  }
#pragma unroll
  for (int off = 32; off >= 1; off >>= 1) {
    s += __shfl_xor(s, off);
    s2 += __shfl_xor(s2, off);
  }
  const float mean = s * (1.f / 512.f);
  const float var = s2 * (1.f / 512.f) - mean * mean;
  const float rstd = rsqrtf(var + 1e-5f);
  float4 g0 = *(const float4*)(g + lane * 8);
  float4 g1 = *(const float4*)(g + lane * 8 + 4);
  float4 b0 = *(const float4*)(bta + lane * 8);
  float4 b1 = *(const float4*)(bta + lane * 8 + 4);
  float gv[8] = {g0.x, g0.y, g0.z, g0.w, g1.x, g1.y, g1.z, g1.w};
  float bv[8] = {b0.x, b0.y, b0.z, b0.w, b1.x, b1.y, b1.z, b1.w};
  s16x8 outv;
#pragma unroll
  for (int e = 0; e < 8; ++e)
    outv[e] = f2b((v[e] - mean) * rstd * gv[e] + bv[e]);
  *(s16x8*)xp = outv;
}

// ---------------- head ----------------------------------------------------
__global__ void __launch_bounds__(256)
head1_kernel(const short* __restrict__ x, const float* __restrict__ w1,
             const float* __restrict__ b1, const float* __restrict__ w2) {
  const int bidx = blockIdx.x;
  const int b = bidx >> 3, seg = bidx & 7;
  const int tid = threadIdx.x;
  __shared__ float xl[512];
  __shared__ float red[256];
  for (int n = tid; n < 512; n += 256)
    xl[n] = b2f(x[((size_t)b * 512 + 511) * 512 + n]);
  __syncthreads();
  const int f = seg * 256 + tid;
  const float* wr = w1 + (size_t)f * 512;
  float hv = 0.f;
  for (int k8 = 0; k8 < 64; ++k8) {
    float4 wa = *(const float4*)(wr + k8 * 8);
    float4 wb = *(const float4*)(wr + k8 * 8 + 4);
    hv += xl[k8 * 8 + 0] * wa.x + xl[k8 * 8 + 1] * wa.y +
          xl[k8 * 8 + 2] * wa.z + xl[k8 * 8 + 3] * wa.w +
          xl[k8 * 8 + 4] * wb.x + xl[k8 * 8 + 5] * wb.y +
          xl[k8 * 8 + 6] * wb.z + xl[k8 * 8 + 7] * wb.w;
  }
  hv += b1[f];
  hv = fmaxf(hv, 0.f);
  red[tid] = hv * w2[f];
  __syncthreads();
  for (int stride = 128; stride > 0; stride >>= 1) {
    if (tid < stride) red[tid] += red[tid + stride];
    __syncthreads();
  }
  if (tid == 0) g_hpart[bidx] = red[0];
}

__global__ void __launch_bounds__(64)
head2_kernel(const float* __restrict__ b2, float* __restrict__ out) {
  const int t = threadIdx.x;
  if (t < 32) {
    float s = 0.f;
#pragma unroll
    for (int c = 0; c < 8; ++c) s += g_hpart[t * 8 + c];
    out[t] = s + b2[0];
  }
}

extern "C" void kernel_launch(void* const* d_in, const int* in_sizes, int n_in,
                              void* d_out, int out_size, void* d_ws, size_t ws_size,
                              hipStream_t stream) {
  (void)in_sizes; (void)n_in; (void)out_size; (void)ws_size;
  const float* src       = (const float*)d_in[0];
  const float* inp_w     = (const float*)d_in[1];
  const float* inp_b     = (const float*)d_in[2];
  const float* in_proj_w = (const float*)d_in[3];
  const float* in_proj_b = (const float*)d_in[4];
  const float* out_w     = (const float*)d_in[5];
  const float* out_b     = (const float*)d_in[6];
  const float* ff_w1     = (const float*)d_in[7];
  const float* ff_b1     = (const float*)d_in[8];
  const float* ff_w2     = (const float*)d_in[9];
  const float* ff_b2     = (const float*)d_in[10];
  const float* ln1_g     = (const float*)d_in[11];
  const float* ln1_b     = (const float*)d_in[12];
  const float* ln2_g     = (const float*)d_in[13];
  const float* ln2_b     = (const float*)d_in[14];
  const float* op_w1     = (const float*)d_in[15];
  const float* op_b1     = (const float*)d_in[16];
  const float* op_w2     = (const float*)d_in[17];
  const float* op_b2     = (const float*)d_in[18];

  short* ws   = (short*)d_ws;
  short* x    = ws;                              //  8,388,608
  short* qkv  = ws + 8388608;                    // 25,165,824
  short* ctx  = qkv + 25165824;                  //  8,388,608
  short* obuf = ctx + 8388608;                   //  8,388,608
  short* h    = qkv;                             // ff hidden spans qkv+ctx

  cvt2_kernel<<<528, 256, 0, stream>>>(src, inp_w);
  pe_kernel<<<512, 256, 0, stream>>>();
  gemm_bt<2><<<512, 256, 0, stream>>>(nullptr, 0, inp_b, x, 16384, 512, 64);

  for (int l = 0; l < 6; ++l) {
    cvt4_kernel<<<1536, 256, 0, stream>>>(
        in_proj_w + (size_t)l * 786432, out_w + (size_t)l * 262144,
        ff_w1 + (size_t)l * 1048576, ff_w2 + (size_t)l * 1048576);
    gemm_bt<0><<<1536, 256, 0, stream>>>(
        x, 0, in_proj_b + l * 1536, qkv, 16384, 1536, 512);
    attn_kernel<<<4096, 256, 0, stream>>>(qkv, ctx);
    gemm_bt<0><<<512, 256, 0, stream>>>(
        ctx, 786432, out_b + l * 512, obuf, 16384, 512, 512);
    ln_kernel<<<4096, 256, 0, stream>>>(x, obuf, ln1_g + l * 512, ln1_b + l * 512);
    gemm_bt<1><<<2048, 256, 0, stream>>>(
        x, 1048576, ff_b1 + l * 2048, h, 16384, 2048, 512);
    gemm_bt<0><<<512, 256, 0, stream>>>(
        h, 2097152, ff_b2 + l * 512, obuf, 16384, 512, 2048);
    ln_kernel<<<4096, 256, 0, stream>>>(x, obuf, ln2_g + l * 512, ln2_b + l * 512);
  }
  head1_kernel<<<256, 256, 0, stream>>>(x, op_w1, op_b1, op_w2);
  head2_kernel<<<1, 64, 0, stream>>>(op_b2, (float*)d_out);
}

// Round 9
// 1645.634 us; speedup vs baseline: 1.0896x; 1.0896x over previous
//
#include <hip/hip_runtime.h>

typedef short s16x8 __attribute__((ext_vector_type(8)));
typedef float f32x4 __attribute__((ext_vector_type(4)));

// device-global scratch (outside d_ws; fully rewritten every launch)
__device__ short g_wbuf[3145728];   // per-layer bf16 weights: inproj|outw|ffw1|ffw2
__device__ short g_srcb[1048576];   // src as bf16 (16384 x 64)
__device__ short g_inpwb[32768];    // inp_w as bf16 (512 x 64)
__device__ float g_pe[262144];      // positional encoding (512 x 512)
__device__ float g_hpart[256];      // head partials

__device__ inline float b2f(short s) {
  union { unsigned int u; float f; } v;
  v.u = ((unsigned int)(unsigned short)s) << 16;
  return v.f;
}
__device__ inline short f2b(float f) {
  union { float f; unsigned int u; } v; v.f = f;
  unsigned int r = (v.u + 0x7fffu + ((v.u >> 16) & 1u)) >> 16;
  return (short)r;
}
__device__ inline s16x8 pack8(float4 a, float4 b) {
  s16x8 r;
  r[0] = f2b(a.x); r[1] = f2b(a.y); r[2] = f2b(a.z); r[3] = f2b(a.w);
  r[4] = f2b(b.x); r[5] = f2b(b.y); r[6] = f2b(b.z); r[7] = f2b(b.w);
  return r;
}

__device__ inline f32x4 mfma16(s16x8 a, s16x8 b, f32x4 c) {
  return __builtin_amdgcn_mfma_f32_16x16x32_bf16(a, b, c, 0, 0, 0);
}

typedef const __attribute__((address_space(1))) void* as1cptr;
typedef __attribute__((address_space(3))) void* as3ptr;
__device__ inline void gl2lds16(const short* g, short* l) {
  __builtin_amdgcn_global_load_lds((as1cptr)g, (as3ptr)l, 16, 0, 0);
}

// ---------------- fp32 -> bf16 conversion kernels --------------------------
__global__ void __launch_bounds__(256)
cvt2_kernel(const float* __restrict__ i0, const float* __restrict__ i1) {
  const int b = blockIdx.x;
  const float* src; short* dst; int base;
  if (b < 512) { src = i0; dst = g_srcb; base = b; }
  else         { src = i1; dst = g_inpwb; base = b - 512; }
  const int idx = (base * 256 + threadIdx.x) * 8;
  float4 a = *(const float4*)(src + idx);
  float4 c = *(const float4*)(src + idx + 4);
  *(s16x8*)(dst + idx) = pack8(a, c);
}

__global__ void __launch_bounds__(256)
cvt4_kernel(const float* __restrict__ i0, const float* __restrict__ i1,
            const float* __restrict__ i2, const float* __restrict__ i3) {
  const int b = blockIdx.x;
  const float* src; short* dst; int base;
  if (b < 384)       { src = i0; dst = g_wbuf;           base = b; }
  else if (b < 512)  { src = i1; dst = g_wbuf +  786432; base = b - 384; }
  else if (b < 1024) { src = i2; dst = g_wbuf + 1048576; base = b - 512; }
  else               { src = i3; dst = g_wbuf + 2097152; base = b - 1024; }
  const int idx = (base * 256 + threadIdx.x) * 8;
  float4 a = *(const float4*)(src + idx);
  float4 c = *(const float4*)(src + idx + 4);
  *(s16x8*)(dst + idx) = pack8(a, c);
}

// ---------------- PE table: g_pe[s][n] ------------------------------------
__global__ void __launch_bounds__(256)
pe_kernel() {
  const int s = blockIdx.x;
  const int n0 = threadIdx.x * 2;
  const float ang = (float)s * expf((float)n0 * -0.0179889460390160f);
  g_pe[s * 512 + n0]     = sinf(ang);
  g_pe[s * 512 + n0 + 1] = cosf(ang);
}

// ---------------- GEMM: C[M,N] = A[M,K] @ W[N,K]^T + epilogue -------------
// BK=64, XOR-swizzled gl2lds staging. 1D grid, bn-major decode
// (bm = id&127, bn = id>>7): same-XCD blocks (stride 8) share one W-tile
// chunk -> per-XCD L2 W traffic /16; A-tiles get XCD affinity (bm%8 fixed).
// EPI: 0 = +bias; 1 = relu(+bias); 2 = embed ((acc+bias)*sqrt512 + PE)
template <int EPI>
__global__ void __launch_bounds__(256, 3)
gemm_bt(const short* __restrict__ Ain, int woff, const float* __restrict__ bias,
        short* __restrict__ C, int M, int N, int K) {
  __shared__ short As[128 * 64];   // 16 KB
  __shared__ short Bs[128 * 64];   // 16 KB
  const int tid  = threadIdx.x;
  const int lane = tid & 63;
  const int wave = tid >> 6;
  const int wr = (wave >> 1) << 6;
  const int wc = (wave & 1) << 6;
  const int ml = lane & 15;
  const int quad = lane >> 4;
  const int bm = blockIdx.x & 127;
  const int bn = blockIdx.x >> 7;

  const short* A = (EPI == 2) ? (const short*)g_srcb : Ain;
  const short* W = (EPI == 2) ? (const short*)g_inpwb : (const short*)(g_wbuf + woff);

  int srow[4], soff[4];
#pragma unroll
  for (int i = 0; i < 4; ++i) {
    const int u = i * 256 + tid;
    srow[i] = u >> 3;
    soff[i] = ((u & 7) ^ ((u >> 3) & 7)) << 3;
  }
  const int rsw = (ml & 7);
  f32x4 acc[4][4] = {};

  for (int k0 = 0; k0 < K; k0 += 64) {
#pragma unroll
    for (int i = 0; i < 4; ++i) {
      gl2lds16(A + (size_t)(bm * 128 + srow[i]) * K + k0 + soff[i],
               As + (i * 256 + tid) * 8);
      gl2lds16(W + (size_t)(bn * 128 + srow[i]) * K + k0 + soff[i],
               Bs + (i * 256 + tid) * 8);
    }
    __syncthreads();
#pragma unroll
    for (int kk = 0; kk < 2; ++kk) {
      const int rchunk = ((kk * 4 + quad) ^ rsw) * 8;
      s16x8 af[4], bfr[4];
#pragma unroll
      for (int i = 0; i < 4; ++i)
        af[i] = *(const s16x8*)(As + (wr + i * 16 + ml) * 64 + rchunk);
#pragma unroll
      for (int j = 0; j < 4; ++j)
        bfr[j] = *(const s16x8*)(Bs + (wc + j * 16 + ml) * 64 + rchunk);
#pragma unroll
      for (int i = 0; i < 4; ++i)
#pragma unroll
        for (int j = 0; j < 4; ++j)
          acc[i][j] = mfma16(af[i], bfr[j], acc[i][j]);
    }
    __syncthreads();
  }

#pragma unroll
  for (int j = 0; j < 4; ++j) {
    const int col = bn * 128 + wc + j * 16 + ml;
    const float bv = bias[col];
#pragma unroll
    for (int i = 0; i < 4; ++i) {
      const int row0 = bm * 128 + wr + i * 16 + quad * 4;
#pragma unroll
      for (int r = 0; r < 4; ++r) {
        float v = acc[i][j][r] + bv;
        if (EPI == 1) v = fmaxf(v, 0.0f);
        if (EPI == 2) {
          const int s = (row0 + r) & 511;
          v = (acc[i][j][r] + bv) * 22.62741699796952f + g_pe[s * 512 + col];
        }
        C[(size_t)(row0 + r) * N + col] = f2b(v);
      }
    }
  }
}

// ---------------- fused attention, single pass, 64-key rounds -------------
// LDS ~23.3 KB; launch_bounds (256,4): VGPR cap ~128 (kernel needs ~115 --
// (256,5) capped at ~102 and spilled sc[] to scratch, R8's 122 MB WRITE_SIZE).
__global__ void __launch_bounds__(256, 4)
attn_kernel(const short* __restrict__ qkv, short* __restrict__ ctx) {
  __shared__ short KT[64 * 72];      // 9216 B  [key][d]
  __shared__ short VT[64 * 72];      // 9216 B  [d][key]
  __shared__ short Pt[32 * 72];      // 4608 B  [qrow][key]
  __shared__ float rcomb[2][2][16];  // [nh][mt][row16]: max, then sums
  const int tid = threadIdx.x;
  const int lane = tid & 63, wave = tid >> 6;
  const int ml = lane & 15, quad = lane >> 4;
  const int mt = wave & 1, nh = wave >> 1;
  const int bx = blockIdx.x;
  const int qt = bx >> 8;
  const int bh = bx & 255;
  const int b = bh >> 3, h = bh & 7;
  const size_t basebs = (size_t)b * 512 * 1536;
  const int hoff = h * 64;

  s16x8 qf0, qf1;
  {
    const int qrow = qt * 32 + mt * 16 + ml;
    const short* qp = qkv + basebs + (size_t)qrow * 1536 + hoff;
    qf0 = *(const s16x8*)(qp + quad * 8);
    qf1 = *(const s16x8*)(qp + 32 + quad * 8);
  }

  // ---- phase 1: all scores into registers (8 rounds x 64 keys) ----
  f32x4 sc[8][2];
#pragma unroll
  for (int rr = 0; rr < 8; ++rr) {
#pragma unroll
    for (int i = 0; i < 2; ++i) {          // stage 64 keys x 64 d
      int u = i * 256 + tid;
      int key = u >> 3;
      int d8 = (u & 7) << 3;
      const short* kp = qkv + basebs + (size_t)(rr * 64 + key) * 1536 + 512 + hoff + d8;
      *(s16x8*)(KT + key * 72 + d8) = *(const s16x8*)kp;
    }
    __syncthreads();
#pragma unroll
    for (int nt = 0; nt < 2; ++nt) {
      const int nrow = nh * 32 + nt * 16 + ml;
      f32x4 sacc = {};
      s16x8 kf0 = *(const s16x8*)(KT + nrow * 72 + quad * 8);
      s16x8 kf1 = *(const s16x8*)(KT + nrow * 72 + 32 + quad * 8);
      sacc = mfma16(qf0, kf0, sacc);
      sacc = mfma16(qf1, kf1, sacc);
      sc[rr][nt] = sacc;
    }
    __syncthreads();
  }

  // ---- exact row max ----
  f32x4 rmx = sc[0][0];
#pragma unroll
  for (int rr = 0; rr < 8; ++rr)
#pragma unroll
    for (int nt = 0; nt < 2; ++nt)
#pragma unroll
      for (int r = 0; r < 4; ++r)
        rmx[r] = fmaxf(rmx[r], sc[rr][nt][r]);
#pragma unroll
  for (int off = 1; off <= 8; off <<= 1)
#pragma unroll
    for (int r = 0; r < 4; ++r)
      rmx[r] = fmaxf(rmx[r], __shfl_xor(rmx[r], off));
  if (ml == 0) {
#pragma unroll
    for (int r = 0; r < 4; ++r)
      rcomb[nh][mt][quad * 4 + r] = rmx[r];
  }
  __syncthreads();
  float rm[4];
#pragma unroll
  for (int r = 0; r < 4; ++r)
    rm[r] = 0.125f * fmaxf(rcomb[0][mt][quad * 4 + r], rcomb[1][mt][quad * 4 + r]);

  // ---- phase 2: exp -> Pt, V^T stage, PV MFMA (8 rounds) ----
  f32x4 oacc[2] = {};
  float psum[4] = {0.f, 0.f, 0.f, 0.f};
#pragma unroll
  for (int rr = 0; rr < 8; ++rr) {
#pragma unroll
    for (int nt = 0; nt < 2; ++nt) {
#pragma unroll
      for (int r = 0; r < 4; ++r) {
        float p = __expf(sc[rr][nt][r] * 0.125f - rm[r]);   // arg <= 0 exactly
        short pb = f2b(p);
        psum[r] += b2f(pb);
        Pt[(mt * 16 + quad * 4 + r) * 72 + nh * 32 + nt * 16 + ml] = pb;
      }
    }
#pragma unroll
    for (int i = 0; i < 4; ++i) {          // stage V^T tile [d][key]
      int u = i * 256 + tid;
      int kp = u >> 5;   // key pair 0..31
      int dp = u & 31;   // d pair 0..31
      const short* vp = qkv + basebs + (size_t)(rr * 64 + kp * 2) * 1536 + 1024 + hoff + dp * 2;
      unsigned int u0 = *(const unsigned int*)vp;
      unsigned int u1 = *(const unsigned int*)(vp + 1536);
      unsigned int w0 = (u0 & 0xffffu) | (u1 << 16);
      unsigned int w1 = (u0 >> 16) | (u1 & 0xffff0000u);
      *(unsigned int*)(VT + (dp * 2) * 72 + kp * 2) = w0;
      *(unsigned int*)(VT + (dp * 2 + 1) * 72 + kp * 2) = w1;
    }
    __syncthreads();   // Pt + VT visible
#pragma unroll
    for (int ks = 0; ks < 2; ++ks) {
      s16x8 pf = *(const s16x8*)(Pt + (mt * 16 + ml) * 72 + ks * 32 + quad * 8);
#pragma unroll
      for (int n2 = 0; n2 < 2; ++n2) {
        const int nd = (nh * 2 + n2) * 16 + ml;
        s16x8 vf = *(const s16x8*)(VT + nd * 72 + ks * 32 + quad * 8);
        oacc[n2] = mfma16(pf, vf, oacc[n2]);
      }
    }
    __syncthreads();   // PV reads done before next-round Pt/VT rewrite
  }

  // ---- row sums ----
#pragma unroll
  for (int off = 1; off <= 8; off <<= 1)
#pragma unroll
    for (int r = 0; r < 4; ++r)
      psum[r] += __shfl_xor(psum[r], off);
  if (ml == 0) {
#pragma unroll
    for (int r = 0; r < 4; ++r)
      rcomb[nh][mt][quad * 4 + r] = psum[r];
  }
  __syncthreads();

#pragma unroll
  for (int r = 0; r < 4; ++r) {
    const int srow = mt * 16 + quad * 4 + r;
    const float l = rcomb[0][mt][quad * 4 + r] + rcomb[1][mt][quad * 4 + r];
    const float rl = 1.0f / l;
    const int grow = qt * 32 + srow;
#pragma unroll
    for (int n2 = 0; n2 < 2; ++n2) {
      const int d = (nh * 2 + n2) * 16 + ml;
      ctx[((size_t)b * 512 + grow) * 512 + hoff + d] = f2b(oacc[n2][r] * rl);
    }
  }
}

// ---------------- residual + layernorm (in-place on x, fp32 params) -------
__global__ void __launch_bounds__(256)
ln_kernel(short* __restrict__ x, const short* __restrict__ o,
          const float* __restrict__ g, const float* __restrict__ bta) {
  const int row = blockIdx.x * 4 + (threadIdx.x >> 6);
  const int lane = threadIdx.x & 63;
  short* xp = x + (size_t)row * 512 + lane * 8;
  const short* op = o + (size_t)row * 512 + lane * 8;
  s16x8 xv = *(const s16x8*)xp;
  s16x8 ov = *(const s16x8*)op;
  float v[8]; float s = 0.f, s2 = 0.f;
#pragma unroll
  for (int e = 0; e < 8; ++e) {
    float f = b2f(xv[e]) + b2f(ov[e]);
    v[e] = f; s += f; s2 += f * f;
  }
#pragma unroll
  for (int off = 32; off >= 1; off >>= 1) {
    s += __shfl_xor(s, off);
    s2 += __shfl_xor(s2, off);
  }
  const float mean = s * (1.f / 512.f);
  const float var = s2 * (1.f / 512.f) - mean * mean;
  const float rstd = rsqrtf(var + 1e-5f);
  float4 g0 = *(const float4*)(g + lane * 8);
  float4 g1 = *(const float4*)(g + lane * 8 + 4);
  float4 b0 = *(const float4*)(bta + lane * 8);
  float4 b1 = *(const float4*)(bta + lane * 8 + 4);
  float gv[8] = {g0.x, g0.y, g0.z, g0.w, g1.x, g1.y, g1.z, g1.w};
  float bv[8] = {b0.x, b0.y, b0.z, b0.w, b1.x, b1.y, b1.z, b1.w};
  s16x8 outv;
#pragma unroll
  for (int e = 0; e < 8; ++e)
    outv[e] = f2b((v[e] - mean) * rstd * gv[e] + bv[e]);
  *(s16x8*)xp = outv;
}

// ---------------- head ----------------------------------------------------
__global__ void __launch_bounds__(256)
head1_kernel(const short* __restrict__ x, const float* __restrict__ w1,
             const float* __restrict__ b1, const float* __restrict__ w2) {
  const int bidx = blockIdx.x;
  const int b = bidx >> 3, seg = bidx & 7;
  const int tid = threadIdx.x;
  __shared__ float xl[512];
  __shared__ float red[256];
  for (int n = tid; n < 512; n += 256)
    xl[n] = b2f(x[((size_t)b * 512 + 511) * 512 + n]);
  __syncthreads();
  const int f = seg * 256 + tid;
  const float* wr = w1 + (size_t)f * 512;
  float hv = 0.f;
  for (int k8 = 0; k8 < 64; ++k8) {
    float4 wa = *(const float4*)(wr + k8 * 8);
    float4 wb = *(const float4*)(wr + k8 * 8 + 4);
    hv += xl[k8 * 8 + 0] * wa.x + xl[k8 * 8 + 1] * wa.y +
          xl[k8 * 8 + 2] * wa.z + xl[k8 * 8 + 3] * wa.w +
          xl[k8 * 8 + 4] * wb.x + xl[k8 * 8 + 5] * wb.y +
          xl[k8 * 8 + 6] * wb.z + xl[k8 * 8 + 7] * wb.w;
  }
  hv += b1[f];
  hv = fmaxf(hv, 0.f);
  red[tid] = hv * w2[f];
  __syncthreads();
  for (int stride = 128; stride > 0; stride >>= 1) {
    if (tid < stride) red[tid] += red[tid + stride];
    __syncthreads();
  }
  if (tid == 0) g_hpart[bidx] = red[0];
}

__global__ void __launch_bounds__(64)
head2_kernel(const float* __restrict__ b2, float* __restrict__ out) {
  const int t = threadIdx.x;
  if (t < 32) {
    float s = 0.f;
#pragma unroll
    for (int c = 0; c < 8; ++c) s += g_hpart[t * 8 + c];
    out[t] = s + b2[0];
  }
}

extern "C" void kernel_launch(void* const* d_in, const int* in_sizes, int n_in,
                              void* d_out, int out_size, void* d_ws, size_t ws_size,
                              hipStream_t stream) {
  (void)in_sizes; (void)n_in; (void)out_size; (void)ws_size;
  const float* src       = (const float*)d_in[0];
  const float* inp_w     = (const float*)d_in[1];
  const float* inp_b     = (const float*)d_in[2];
  const float* in_proj_w = (const float*)d_in[3];
  const float* in_proj_b = (const float*)d_in[4];
  const float* out_w     = (const float*)d_in[5];
  const float* out_b     = (const float*)d_in[6];
  const float* ff_w1     = (const float*)d_in[7];
  const float* ff_b1     = (const float*)d_in[8];
  const float* ff_w2     = (const float*)d_in[9];
  const float* ff_b2     = (const float*)d_in[10];
  const float* ln1_g     = (const float*)d_in[11];
  const float* ln1_b     = (const float*)d_in[12];
  const float* ln2_g     = (const float*)d_in[13];
  const float* ln2_b     = (const float*)d_in[14];
  const float* op_w1     = (const float*)d_in[15];
  const float* op_b1     = (const float*)d_in[16];
  const float* op_w2     = (const float*)d_in[17];
  const float* op_b2     = (const float*)d_in[18];

  short* ws   = (short*)d_ws;
  short* x    = ws;                              //  8,388,608
  short* qkv  = ws + 8388608;                    // 25,165,824
  short* ctx  = qkv + 25165824;                  //  8,388,608
  short* obuf = ctx + 8388608;                   //  8,388,608
  short* h    = qkv;                             // ff hidden spans qkv+ctx

  cvt2_kernel<<<528, 256, 0, stream>>>(src, inp_w);
  pe_kernel<<<512, 256, 0, stream>>>();
  gemm_bt<2><<<512, 256, 0, stream>>>(nullptr, 0, inp_b, x, 16384, 512, 64);

  for (int l = 0; l < 6; ++l) {
    cvt4_kernel<<<1536, 256, 0, stream>>>(
        in_proj_w + (size_t)l * 786432, out_w + (size_t)l * 262144,
        ff_w1 + (size_t)l * 1048576, ff_w2 + (size_t)l * 1048576);
    gemm_bt<0><<<1536, 256, 0, stream>>>(
        x, 0, in_proj_b + l * 1536, qkv, 16384, 1536, 512);
    attn_kernel<<<4096, 256, 0, stream>>>(qkv, ctx);
    gemm_bt<0><<<512, 256, 0, stream>>>(
        ctx, 786432, out_b + l * 512, obuf, 16384, 512, 512);
    ln_kernel<<<4096, 256, 0, stream>>>(x, obuf, ln1_g + l * 512, ln1_b + l * 512);
    gemm_bt<1><<<2048, 256, 0, stream>>>(
        x, 1048576, ff_b1 + l * 2048, h, 16384, 2048, 512);
    gemm_bt<0><<<512, 256, 0, stream>>>(
        h, 2097152, ff_b2 + l * 512, obuf, 16384, 512, 2048);
    ln_kernel<<<4096, 256, 0, stream>>>(x, obuf, ln2_g + l * 512, ln2_b + l * 512);
  }
  head1_kernel<<<256, 256, 0, stream>>>(x, op_w1, op_b1, op_w2);
  head2_kernel<<<1, 64, 0, stream>>>(op_b2, (float*)d_out);
}